// Round 5
// baseline (141.655 us; speedup 1.0000x reference)
//
#include <hip/hip_runtime.h>
#include <hip/hip_bf16.h>

#define N_ROWS 131072
#define K_MIX  256
#define D_DIM  128
#define KHALF  128                 // components staged per epoch (K-split)
#define LDSB_STRIDE 136            // shorts per B row: 128 + 8 pad (rows 272 B, 16B aligned)
#define ROWS_PER_BLOCK 128         // 4 waves x 32 rows

typedef float  f32x4  __attribute__((ext_vector_type(4)));
typedef short  bf16x8 __attribute__((ext_vector_type(8)));

#define LOG2E_F 1.44269504088896340736f
#define LN2_F   0.69314718055994530942f

#if __has_builtin(__builtin_amdgcn_exp2f)
#define EXP2F(x) __builtin_amdgcn_exp2f(x)
#else
#define EXP2F(x) exp2f(x)
#endif
#if __has_builtin(__builtin_amdgcn_logf)
#define LOG2F(x) __builtin_amdgcn_logf(x)
#else
#define LOG2F(x) __log2f(x)
#endif

__device__ inline bf16x8 pack8(float4 a, float4 b) {
    union { bf16x8 v; __hip_bfloat162 h[4]; } u;
    u.h[0] = __float22bfloat162_rn(make_float2(a.x, a.y));
    u.h[1] = __float22bfloat162_rn(make_float2(a.z, a.w));
    u.h[2] = __float22bfloat162_rn(make_float2(b.x, b.y));
    u.h[3] = __float22bfloat162_rn(make_float2(b.z, b.w));
    return u.v;
}

// K-split fused kernel: stage 128 of the 256 components per epoch (34.8 KB LDS
// -> 4 blocks/CU = 16 waves/CU, double round-4's occupancy). Online-LSE state
// (m_run,s_run; 16 regs) and the packed bf16 x-fragments (a0/a1; 32 regs) live
// across the epoch boundary — both small enough for the allocator's 128-reg
// target (round-3 lesson: 64-reg xv across a phase gets spilled, 32-reg a-frags
// don't). Epoch loop is #pragma unroll 1 + double-barriered: nothing hoists
// across compute (rounds 1-3 spill lesson).
__global__ __launch_bounds__(256, 2)
void mixture_fused(const float* __restrict__ x,
                   const float* __restrict__ mu,
                   const float* __restrict__ prec,
                   float* __restrict__ out)
{
    __shared__ __align__(16) unsigned short sB[KHALF * LDSB_STRIDE];  // 34816 B
    __shared__ float sMusq[KHALF];      // -0.5*log2e*musq for staged half
    __shared__ float sRed[4];

    const int tid  = threadIdx.x;
    const int lane = tid & 63;
    const int wave = tid >> 6;          // 0..3
    const int low4 = lane & 15;
    const int q    = lane >> 4;

    const float4* x4 = (const float4*)x;
    const float4* p4 = (const float4*)prec;
    const int rbase = blockIdx.x * ROWS_PER_BLOCK + wave * 32;
    const float4* xr0 = x4 + (size_t)(rbase + low4) * 32;
    const float4* xr1 = x4 + (size_t)(rbase + low4 + 16) * 32;

    // ---- phase 1: load this wave's 32 x-rows (16 independent float4) ----
    float4 xv[4][4];
    #pragma unroll
    for (int k = 0; k < 4; ++k) {
        const int d4 = k * 8 + q * 2;
        xv[k][0] = xr0[d4]; xv[k][1] = xr0[d4 + 1];
        xv[k][2] = xr1[d4]; xv[k][3] = xr1[d4 + 1];
    }

    // ---- phase 2: xsq partials + pack A-fragments (xv dies here).
    //      prec read straight from global: 512 B, L1-hot. base-2 pre-scale. ----
    float xs;
    bf16x8 a0[4], a1[4];
    {
        float xsA = 0.f, xsB = 0.f;
        #pragma unroll
        for (int k = 0; k < 4; ++k) {
            const int d4 = k * 8 + q * 2;
            float4 pa = p4[d4];
            float4 pb = p4[d4 + 1];
            pa.x *= LOG2E_F; pa.y *= LOG2E_F; pa.z *= LOG2E_F; pa.w *= LOG2E_F;
            pb.x *= LOG2E_F; pb.y *= LOG2E_F; pb.z *= LOG2E_F; pb.w *= LOG2E_F;
            xsA += pa.x*xv[k][0].x*xv[k][0].x + pa.y*xv[k][0].y*xv[k][0].y
                 + pa.z*xv[k][0].z*xv[k][0].z + pa.w*xv[k][0].w*xv[k][0].w;
            xsB += pb.x*xv[k][1].x*xv[k][1].x + pb.y*xv[k][1].y*xv[k][1].y
                 + pb.z*xv[k][1].z*xv[k][1].z + pb.w*xv[k][1].w*xv[k][1].w;
            xsA += pa.x*xv[k][2].x*xv[k][2].x + pa.y*xv[k][2].y*xv[k][2].y
                 + pa.z*xv[k][2].z*xv[k][2].z + pa.w*xv[k][2].w*xv[k][2].w;
            xsB += pb.x*xv[k][3].x*xv[k][3].x + pb.y*xv[k][3].y*xv[k][3].y
                 + pb.z*xv[k][3].z*xv[k][3].z + pb.w*xv[k][3].w*xv[k][3].w;
            a0[k] = pack8(xv[k][0], xv[k][1]);
            a1[k] = pack8(xv[k][2], xv[k][3]);
        }
        xs = xsA + xsB;
    }

    // per-lane online-LSE state, lives across both epochs
    float m_run[2][4], s_run[2][4];
    #pragma unroll
    for (int m = 0; m < 2; ++m)
        #pragma unroll
        for (int i = 0; i < 4; ++i) { m_run[m][i] = -3.0e38f; s_run[m][i] = 0.f; }

    float lacc = 0.f;    // per-lane partial of (0.5*xsq2 - lse2), base-2 domain

    // ---- epoch loop: stage components [e*128, e*128+128) then MFMA+fold ----
    #pragma unroll 1
    for (int e = 0; e < 2; ++e) {
        if (e) __syncthreads();   // all reads of sB from prev epoch done

        // stage: 4096 float4s of this mu-half; 32 consecutive threads per row
        #pragma unroll 4
        for (int i = 0; i < 16; ++i) {
            const int idx = i * 256 + tid;
            const int row = idx >> 5;            // local component 0..127
            const int c4  = idx & 31;
            float4 mv = ((const float4*)mu)[e * 4096 + idx];
            float4 pv = p4[c4];
            float px = mv.x * pv.x * LOG2E_F, py = mv.y * pv.y * LOG2E_F;
            float pz = mv.z * pv.z * LOG2E_F, pw = mv.w * pv.w * LOG2E_F;
            union { ushort4 u4; __hip_bfloat162 h[2]; } hh;
            hh.h[0] = __float22bfloat162_rn(make_float2(px, py));
            hh.h[1] = __float22bfloat162_rn(make_float2(pz, pw));
            *(ushort4*)&sB[row * LDSB_STRIDE + c4 * 4] = hh.u4;   // pad never read
            float ps = px * mv.x + py * mv.y + pz * mv.z + pw * mv.w;
            ps += __shfl_xor(ps, 1);  ps += __shfl_xor(ps, 2);
            ps += __shfl_xor(ps, 4);  ps += __shfl_xor(ps, 8);
            ps += __shfl_xor(ps, 16);
            if ((tid & 31) == 0) sMusq[row] = -0.5f * ps;
        }
        __syncthreads();

        // MFMA over the 8 column-frags of this half
        f32x4 acc[2][8];
        #pragma unroll
        for (int c = 0; c < 8; ++c) {
            float mneg = sMusq[c * 16 + low4];   // = -0.5*log2e*musq[col]
            #pragma unroll
            for (int i = 0; i < 4; ++i) { acc[0][c][i] = mneg; acc[1][c][i] = mneg; }
        }

        #pragma unroll
        for (int k = 0; k < 4; ++k) {
            #pragma unroll
            for (int c = 0; c < 8; ++c) {
                const unsigned short* bp =
                    &sB[(c * 16 + low4) * LDSB_STRIDE + k * 32 + q * 8];
                bf16x8 b = *(const bf16x8*)bp;   // ds_read_b128
                acc[0][c] = __builtin_amdgcn_mfma_f32_16x16x32_bf16(a0[k], b, acc[0][c], 0, 0, 0);
                acc[1][c] = __builtin_amdgcn_mfma_f32_16x16x32_bf16(a1[k], b, acc[1][c], 0, 0, 0);
            }
        }

        // fold this half into running (m,s) — acc registers die here
        #pragma unroll
        for (int m = 0; m < 2; ++m) {
            #pragma unroll
            for (int i = 0; i < 4; ++i) {
                float v0 = acc[m][0][i], v1 = acc[m][1][i];
                float v2 = acc[m][2][i], v3 = acc[m][3][i];
                float v4 = acc[m][4][i], v5 = acc[m][5][i];
                float v6 = acc[m][6][i], v7 = acc[m][7][i];
                float hmax = fmaxf(fmaxf(fmaxf(v0, v1), fmaxf(v2, v3)),
                                   fmaxf(fmaxf(v4, v5), fmaxf(v6, v7)));
                float hsum = EXP2F(v0 - hmax) + EXP2F(v1 - hmax)
                           + EXP2F(v2 - hmax) + EXP2F(v3 - hmax)
                           + EXP2F(v4 - hmax) + EXP2F(v5 - hmax)
                           + EXP2F(v6 - hmax) + EXP2F(v7 - hmax);
                float mr = m_run[m][i];
                float mn = fmaxf(mr, hmax);
                s_run[m][i] = s_run[m][i] * EXP2F(mr - mn) + hsum * EXP2F(hmax - mn);
                m_run[m][i] = mn;
            }
        }
    }

    // ---- merge (m,s) across the 16 col-lanes, accumulate ----
    #pragma unroll
    for (int m = 0; m < 2; ++m) {
        #pragma unroll
        for (int i = 0; i < 4; ++i) {
            float mr = m_run[m][i], sr = s_run[m][i];
            #pragma unroll
            for (int step = 1; step <= 8; step <<= 1) {
                float mo = __shfl_xor(mr, step);
                float so = __shfl_xor(sr, step);
                float mn = fmaxf(mr, mo);
                sr = sr * EXP2F(mr - mn) + so * EXP2F(mo - mn);
                mr = mn;
            }
            if (low4 == 0) lacc -= mr + LOG2F(sr);
        }
    }
    lacc += 0.5f * xs;
    lacc *= LN2_F;   // back to natural log

    // ---- block reduction, one atomic ----
    lacc += __shfl_xor(lacc, 32); lacc += __shfl_xor(lacc, 16);
    lacc += __shfl_xor(lacc, 8);  lacc += __shfl_xor(lacc, 4);
    lacc += __shfl_xor(lacc, 2);  lacc += __shfl_xor(lacc, 1);
    if (lane == 0) sRed[wave] = lacc;
    __syncthreads();
    if (tid == 0) atomicAdd(out, sRed[0] + sRed[1] + sRed[2] + sRed[3]);
}

extern "C" void kernel_launch(void* const* d_in, const int* in_sizes, int n_in,
                              void* d_out, int out_size, void* d_ws, size_t ws_size,
                              hipStream_t stream) {
    const float* x    = (const float*)d_in[0];
    const float* mu   = (const float*)d_in[1];
    const float* prec = (const float*)d_in[2];
    float* out = (float*)d_out;

    hipMemsetAsync(d_out, 0, sizeof(float), stream);
    mixture_fused<<<N_ROWS / ROWS_PER_BLOCK, 256, 0, stream>>>(x, mu, prec, out);
}